// Round 7
// baseline (115.604 us; speedup 1.0000x reference)
//
#include <hip/hip_runtime.h>
#include <math.h>

typedef unsigned long long ull;

// Problem constants (from setup_inputs): B=64, G=4999, P=50
constexpr int Bc = 64;
constexpr int Gc = 4999;
constexpr int Pc = 50;

constexpr int RUN   = 1024;          // elements per sorted run
constexpr int NRUN  = 5;             // runs per row (5*1024 = 5120 >= G)
constexpr int NPAD  = NRUN * RUN;
constexpr int TC    = 128;           // chunk_sort threads
constexpr int EC    = 8;             // chunk_sort elems/thread
constexpr int LPW4  = 21;            // genes per lane in es phase
constexpr int PADG  = 256 * LPW4;    // padded gene count = 5376
constexpr int QSPAN = 64 * LPW4;     // genes per quarter = 1344
constexpr ull PADKEY = 0xFFFFFFFFFFFFFFFFull;

__device__ __forceinline__ ull shfl_xor64(ull v, int lm) {
    int lo = __shfl_xor((int)(unsigned)(v & 0xFFFFFFFFull), lm, 64);
    int hi = __shfl_xor((int)(unsigned)(v >> 32), lm, 64);
    return ((ull)(unsigned)hi << 32) | (unsigned)lo;
}

// ---------------------------------------------------------------------------
// Kernel 1: sort one 1024-element chunk. NEW geometry: 128 thr x 8 elems.
// Register stages j<=4 (VALU, off the LDS pipe) -> shuffle stages 27 (was
// 33), bpermutes/elem 54 (was 66), and only ONE LDS sweep (kk=1024, j=512)
// vs 3. 2-wave blocks pack ~2.5/CU (straggler 1.2x vs 1.6x at 4-wave).
// key = (~m)<<32 | idx (unique): ascending u64 == descending value, stable
// by index (== stable argsort(-x)).
// Blocks with r==0 also pack pathway bits (consumed by next launch — safe).
// ---------------------------------------------------------------------------
__global__ __launch_bounds__(TC) void chunk_sort(
    const float* __restrict__ expr, const float* __restrict__ pathway,
    ull* __restrict__ runs, ull* __restrict__ pbits, int P, int G)
{
    __shared__ ull key[RUN];
    const int r = blockIdx.x, b = blockIdx.y, tid = threadIdx.x;
    const int lane = tid & 63;
    const int base = tid * EC;
    const float* row = expr + (size_t)b * G;
    const int gbase = r * RUN + base;

    ull v[EC];
    if (gbase + EC <= G) {
        const float4* row4 = (const float4*)(row + r * RUN);
#pragma unroll
        for (int f = 0; f < 2; ++f) {
            float4 x = row4[tid * 2 + f];
            float xs[4] = {x.x, x.y, x.z, x.w};
#pragma unroll
            for (int c = 0; c < 4; ++c) {
                int o = f * 4 + c;
                unsigned u = __float_as_uint(xs[c]);
                unsigned m = (u >> 31) ? ~u : (u | 0x80000000u);  // monotone
                v[o] = ((ull)(~m) << 32) | (unsigned)(gbase + o);
            }
        }
    } else {
#pragma unroll
        for (int o = 0; o < EC; ++o) {
            int i = gbase + o;
            if (i < G) {
                unsigned u = __float_as_uint(row[i]);
                unsigned m = (u >> 31) ? ~u : (u | 0x80000000u);
                v[o] = ((ull)(~m) << 32) | (unsigned)i;
            } else {
                v[o] = PADKEY;
            }
        }
    }

    for (int kk = 2; kk <= RUN; kk <<= 1) {
        const int j0 = kk >> 1;
        // LDS stage: only j=512 (kk=1024) is cross-wave at 128thr x 8elem
        if (j0 >= 512) {
#pragma unroll
            for (int o = 0; o < EC; ++o) key[base + o] = v[o];
            __syncthreads();
            for (int t = tid; t < RUN / 2; t += TC) {      // 4 pair-iters
                int i  = t;                                // j=512: i=t, ix=t|512
                int ix = t | 512;
                ull a = key[i], c = key[ix];
                bool up = ((i & kk) == 0);                 // true (i<512)
                if ((a > c) == up) { key[i] = c; key[ix] = a; }
            }
            __syncthreads();
#pragma unroll
            for (int o = 0; o < EC; ++o) v[o] = key[base + o];
        }
        // wave-shuffle stages: j = min(j0,256) .. 8 (lm = j/8 in 1..32)
        int jstart = (j0 > 256) ? 256 : j0;
        for (int j = jstart; j >= EC; j >>= 1) {
            int lm = j >> 3;
            // kk >= 16 in all shuffle stages -> base&kk uniform over o
            bool takeMin = (((lane & lm) == 0) == ((base & kk) == 0));
#pragma unroll
            for (int o = 0; o < EC; ++o) {
                ull c = shfl_xor64(v[o], lm);
                ull mn = (v[o] < c) ? v[o] : c;
                ull mx = (v[o] < c) ? c : v[o];
                v[o] = takeMin ? mn : mx;
            }
        }
        // register stages: j = 4, 2, 1 within the 8-elem array
#pragma unroll
        for (int j = 4; j >= 1; j >>= 1) {
            if (j < kk) {
#pragma unroll
                for (int o = 0; o < EC; ++o) {
                    if ((o & j) == 0) {
                        bool up = (((base + o) & kk) == 0);
                        ull a = v[o], c = v[o | j];
                        if ((a > c) == up) { v[o] = c; v[o | j] = a; }
                    }
                }
            }
        }
    }

    // coalesced store: 4x ulonglong2 per thread (64B contiguous)
    ulonglong2* dst2 = (ulonglong2*)(runs + ((size_t)b * NRUN + r) * RUN + base);
#pragma unroll
    for (int o = 0; o < EC; o += 2) {
        ulonglong2 t; t.x = v[o]; t.y = v[o + 1];
        dst2[o / 2] = t;
    }

    // Folded pathway pack: blocks with r==0 (64 blocks x 128 thr = 8192 >= G)
    if (r == 0) {
        int g = b * TC + tid;
        if (g < G) {
            ull m = 0;
#pragma unroll
            for (int p = 0; p < Pc; ++p)
                if (pathway[(size_t)p * G + g] > 0.0f) m |= (1ull << p);
            pbits[g] = m;
        }
    }
}

// ---------------------------------------------------------------------------
// Kernel 2: rank + scatter, REBALANCED: grid (20,64) x 256 (4-wave blocks,
// uniform ~20 waves/CU, no 16-wave straggler blocks). Block (rg,b) stages
// all 5 runs (40 KB LDS, ulonglong2 loads) and ranks elements
// [rg*256, rg*256+256), one per thread: rank = own-run pos + 4 binary
// searches. Keys unique -> exact bijection onto [0,G). Single fused 16B
// scatter: wp[rank] = { pbits[idx], |v|^0.25 bits }  (R5/R6-verified).
// ---------------------------------------------------------------------------
__global__ __launch_bounds__(256) void rank_scatter(
    const ull* __restrict__ runs, const ull* __restrict__ pbits,
    ulonglong2* __restrict__ wp, int G)
{
    __shared__ ull runsLDS[NPAD];   // 40960 B
    const int rg = blockIdx.x, b = blockIdx.y, tid = threadIdx.x;

    const ulonglong2* r2 = (const ulonglong2*)(runs + (size_t)b * NPAD);
    ulonglong2* l2 = (ulonglong2*)runsLDS;
    for (int i = tid; i < NPAD / 2; i += 256) l2[i] = r2[i];   // 10 iters
    __syncthreads();

    const int e = rg * 256 + tid;           // 0..5119
    const ull keyv = runsLDS[e];
    if (keyv == PADKEY) return;             // padding

    const int idx = (int)(unsigned)(keyv & 0xFFFFFFFFu);
    const ull pb = pbits[idx];              // issued early, hides under searches

    const int run = e >> 10;
    int rank = e & 1023;                    // own-run position (stable)
#pragma unroll
    for (int rr = 0; rr < NRUN; ++rr) {
        if (rr == run) continue;
        const ull* arr = &runsLDS[rr * RUN];
        int pos = 0;
#pragma unroll
        for (int s = RUN; s >= 1; s >>= 1) {
            int np = pos + s;
            if (np <= RUN && arr[np - 1] < keyv) pos = np;
        }
        rank += pos;
    }

    unsigned m = ~((unsigned)(keyv >> 32));
    unsigned absbits = ((m >> 31) ? m : ~m) & 0x7FFFFFFFu;
    float av = __uint_as_float(absbits);
    ulonglong2 t;
    t.x = pb;
    t.y = (ull)__float_as_uint(sqrtf(sqrtf(av)));   // |v|^0.25
    wp[(size_t)b * G + rank] = t;
}

// ---------------------------------------------------------------------------
// Kernel 3: enrichment scores (R6-verified). Grid (4,64) x 1024 (16 waves):
// wave w = pathway quad qg=w>>2 x gene quarter h=w&3. Norm-factored scan +
// constant-bound (21) unrolled loops; LDS padded to 5376 with zero-step hits.
// ---------------------------------------------------------------------------
__global__ __launch_bounds__(1024) void es_kernel(
    const ulonglong2* __restrict__ wp, float* __restrict__ out,
    int B, int P, int G)
{
    __shared__ float    swq[PADG];   // 21504 B
    __shared__ unsigned sm32[PADG];  // 21504 B
    __shared__ double   cSW[4][4][4];
    __shared__ int      cSH[4][4][4];
    __shared__ double   cBV[4][4][4];
    __shared__ double   cBR[4][4][4];

    const int pg = blockIdx.x;
    const int b  = blockIdx.y;
    const int tid = threadIdx.x;
    const int pbeg = pg * 13;
    const int pend = (pbeg + 13 < P) ? (pbeg + 13) : P;

    for (int i = tid; i < PADG; i += 1024) {
        if (i < G) {
            ulonglong2 t = wp[(size_t)b * G + i];
            swq[i]  = __uint_as_float((unsigned)t.y);
            sm32[i] = (unsigned)(t.x >> pbeg);
        } else {
            swq[i]  = 0.0f;
            sm32[i] = 0xFFFFFFFFu;          // pad = all-hit with wv=0
        }
    }
    __syncthreads();

    const int lane = tid & 63;
    const int w  = tid >> 6;        // 0..15
    const int qg = w >> 2;          // pathway quad 0..3
    const int h  = w & 3;           // gene quarter 0..3
    const int sh4 = qg * 4;

    const int lg = h * 64 + lane;   // chunk id 0..255
    const int start = lg * LPW4;
    int npads = start + LPW4 - G;
    npads = (npads < 0) ? 0 : ((npads > LPW4) ? LPW4 : npads);

    // Pass A: per-chunk (sum w*hit, #hit incl. pads), constant-bound unrolled
    double sw[4] = {0.0, 0.0, 0.0, 0.0};
    int shl[4] = {0, 0, 0, 0};
#pragma unroll
    for (int k = 0; k < LPW4; ++k) {
        int s = start + k;
        unsigned b4 = sm32[s] >> sh4;
        double wv = (double)swq[s];
#pragma unroll
        for (int q = 0; q < 4; ++q) {
            if ((b4 >> q) & 1u) { sw[q] += wv; shl[q]++; }
        }
    }
    // wave totals (real hit counts = shl - npads) -> LDS
#pragma unroll
    for (int q = 0; q < 4; ++q) {
        double s_ = sw[q]; int c_ = shl[q] - npads;
#pragma unroll
        for (int off = 1; off < 64; off <<= 1) {
            s_ += __shfl_xor(s_, off, 64);
            c_ += __shfl_xor(c_, off, 64);
        }
        if (lane == 0) { cSW[qg][h][q] = s_; cSH[qg][h][q] = c_; }
    }
    __syncthreads();

    // Quarter gene counts (real): Qc[h'] = clamp(G - h'*1344, 0, 1344)
    int Qc[4];
#pragma unroll
    for (int hh = 0; hh < 4; ++hh) {
        int c = G - hh * QSPAN;
        Qc[hh] = (c < 0) ? 0 : ((c > QSPAN) ? QSPAN : c);
    }

    // Totals, norm-factored constants, per-lane exclusive prefix
    double negE[4], normq[4], runn[4];
    int shtot[4];
#pragma unroll
    for (int q = 0; q < 4; ++q) {
        double st = 0.0; int ct = 0;
#pragma unroll
        for (int hh = 0; hh < 4; ++hh) { st += cSW[qg][hh][q]; ct += cSH[qg][hh][q]; }
        shtot[q] = ct;
        double d = 1.0 / fmax((double)(G - ct), 1.0);     // inv_denom
        double e = (st > 0.0) ? d * st : d;               // e = inv_denom/norm
        negE[q]  = -e;
        normq[q] = (st > 0.0) ? 1.0 / st : 1.0;
        double offq = 0.0;
        for (int hh = 0; hh < h; ++hh)
            offq += cSW[qg][hh][q] - (double)(Qc[hh] - cSH[qg][hh][q]) * e;
        double csum = sw[q] - (double)(LPW4 - shl[q]) * e;
        double x = csum;
#pragma unroll
        for (int off = 1; off < 64; off <<= 1) {
            double vv = __shfl_up(x, off, 64);
            if (lane >= off) x += vv;
        }
        runn[q] = x - csum + offq;          // exclusive prefix + quarter offset
    }

    // Pass C: constant-bound unrolled scan, no muls in the body
    double bestv[4] = {-1.0, -1.0, -1.0, -1.0};
    double bestr[4] = {0.0, 0.0, 0.0, 0.0};
    int besti[4] = {0x7FFFFFFF, 0x7FFFFFFF, 0x7FFFFFFF, 0x7FFFFFFF};
#pragma unroll
    for (int k = 0; k < LPW4; ++k) {
        int s = start + k;
        unsigned b4 = sm32[s] >> sh4;
        double wv = (double)swq[s];
#pragma unroll
        for (int q = 0; q < 4; ++q) {
            runn[q] += ((b4 >> q) & 1u) ? wv : negE[q];
            double a = fabs(runn[q]);
            if (a > bestv[q]) { bestv[q] = a; bestr[q] = runn[q]; besti[q] = s; }
        }
    }
    // wave-level argmax reduce (first occurrence within quarter)
#pragma unroll
    for (int q = 0; q < 4; ++q) {
#pragma unroll
        for (int off = 1; off < 64; off <<= 1) {
            double ov  = __shfl_xor(bestv[q], off, 64);
            double orr = __shfl_xor(bestr[q], off, 64);
            int    oi  = __shfl_xor(besti[q], off, 64);
            if (ov > bestv[q] || (ov == bestv[q] && oi < besti[q])) {
                bestv[q] = ov; bestr[q] = orr; besti[q] = oi;
            }
        }
        if (lane == 0) { cBV[qg][h][q] = bestv[q]; cBR[qg][h][q] = bestr[q]; }
    }
    __syncthreads();

    // cross-quarter combine + rescale + write (quarters ordered by gene
    // index, so strict > keeps the first occurrence on ties)
    if (h == 0 && lane == 0) {
#pragma unroll
        for (int q = 0; q < 4; ++q) {
            double bv = cBV[qg][0][q];
            double br = cBR[qg][0][q];
#pragma unroll
            for (int hh = 1; hh < 4; ++hh) {
                double v_ = cBV[qg][hh][q];
                if (v_ > bv) { bv = v_; br = cBR[qg][hh][q]; }
            }
            int p = pbeg + sh4 + q;
            if (p < pend)
                out[(size_t)b * P + p] =
                    (shtot[q] > 0) ? (float)(br * normq[q]) : 0.0f;
        }
    }
}

extern "C" void kernel_launch(void* const* d_in, const int* in_sizes, int n_in,
                              void* d_out, int out_size, void* d_ws, size_t ws_size,
                              hipStream_t stream) {
    const float* expr    = (const float*)d_in[0];   // [B, G]
    const float* pathway = (const float*)d_in[1];   // [P, G]
    float* out = (float*)d_out;                     // [B, P]

    // workspace layout (bytes):
    //   pbits ull[5120]        @ 0        (40960)
    //   runs  ull[320*1024]    @ 40960    (2621440 -> ends 2662400)
    //   wp    ull2[B*G]        @ 2662400  (5118976 -> ends 7781376)  ~7.8 MB
    char* ws = (char*)d_ws;
    ull*        pbits = (ull*)ws;
    ull*        runs  = (ull*)(ws + 40960);
    ulonglong2* wp    = (ulonglong2*)(ws + 2662400);

    chunk_sort<<<dim3(NRUN, Bc), dim3(TC), 0, stream>>>(
        expr, pathway, runs, pbits, Pc, Gc);
    rank_scatter<<<dim3(20, Bc), dim3(256), 0, stream>>>(runs, pbits, wp, Gc);
    es_kernel<<<dim3(4, Bc), dim3(1024), 0, stream>>>(
        wp, out, Bc, Pc, Gc);
}

// Round 8
// 102.474 us; speedup vs baseline: 1.1281x; 1.1281x over previous
//
#include <hip/hip_runtime.h>
#include <math.h>

typedef unsigned long long ull;

// Problem constants (from setup_inputs): B=64, G=4999, P=50
constexpr int Bc = 64;
constexpr int Gc = 4999;
constexpr int Pc = 50;

constexpr int RUN   = 1024;          // elements per sorted run
constexpr int NRUN  = 5;             // runs per row (5*1024 = 5120 >= G)
constexpr int NPAD  = NRUN * RUN;
constexpr int LPW4  = 21;            // genes per lane in es phase
constexpr int PADG  = 256 * LPW4;    // padded gene count = 5376
constexpr int QSPAN = 64 * LPW4;     // genes per quarter = 1344
constexpr ull PADKEY = 0xFFFFFFFFFFFFFFFFull;

// ---------------------------------------------------------------------------
// Cross-lane xor exchange for 64-bit values. Lane-masks 1,2,8 go through DPP
// (VALU pipe, ~2cy, no LDS): xor1 = quad_perm[1,0,3,2] (0xB1), xor2 =
// quad_perm[2,3,0,1] (0x4E), xor8 = row_ror:8 (0x128; (i+8)%16 == i^8 within
// each 16-lane DPP row). Masks 4,16,32 stay on ds_bpermute via __shfl_xor.
// This moves 20 of the sort's 33 cross-lane stages off the LDS pipe.
// ---------------------------------------------------------------------------
template<int LM>
__device__ __forceinline__ ull shx64(ull v) {
    int lo = (int)(unsigned)(v & 0xFFFFFFFFull);
    int hi = (int)(unsigned)(v >> 32);
    if constexpr (LM == 1) {
        lo = __builtin_amdgcn_update_dpp(lo, lo, 0xB1, 0xF, 0xF, false);
        hi = __builtin_amdgcn_update_dpp(hi, hi, 0xB1, 0xF, 0xF, false);
    } else if constexpr (LM == 2) {
        lo = __builtin_amdgcn_update_dpp(lo, lo, 0x4E, 0xF, 0xF, false);
        hi = __builtin_amdgcn_update_dpp(hi, hi, 0x4E, 0xF, 0xF, false);
    } else if constexpr (LM == 8) {
        lo = __builtin_amdgcn_update_dpp(lo, lo, 0x128, 0xF, 0xF, false);
        hi = __builtin_amdgcn_update_dpp(hi, hi, 0x128, 0xF, 0xF, false);
    } else {
        lo = __shfl_xor(lo, LM, 64);
        hi = __shfl_xor(hi, LM, 64);
    }
    return ((ull)(unsigned)hi << 32) | (unsigned)lo;
}

template<int KK, int LM>
__device__ __forceinline__ void sstage(ull v[4], int tid, int base) {
    bool takeMin = (((tid & LM) == 0) == ((base & KK) == 0));
#pragma unroll
    for (int o = 0; o < 4; ++o) {
        ull c = shx64<LM>(v[o]);
        ull mn = (v[o] < c) ? v[o] : c;
        ull mx = (v[o] < c) ? c : v[o];
        v[o] = takeMin ? mn : mx;
    }
}

template<int KK>
__device__ __forceinline__ void rstage(ull v[4], int base) {
#pragma unroll
    for (int j = 2; j >= 1; j >>= 1) {
        if (j < KK) {
#pragma unroll
            for (int o = 0; o < 4; ++o) {
                if ((o & j) == 0) {
                    bool up = (((base + o) & KK) == 0);
                    ull a = v[o], c = v[o | j];
                    if ((a > c) == up) { v[o] = c; v[o | j] = a; }
                }
            }
        }
    }
}

// shuffle cascade (j = min(KK/2,128) .. 4, lm = j>>2) + register tail (j=2,1)
template<int KK>
__device__ __forceinline__ void sphase(ull v[4], int tid, int base) {
    if constexpr (KK / 2 >= 128) sstage<KK, 32>(v, tid, base);
    if constexpr (KK / 2 >= 64)  sstage<KK, 16>(v, tid, base);
    if constexpr (KK / 2 >= 32)  sstage<KK, 8>(v, tid, base);
    if constexpr (KK / 2 >= 16)  sstage<KK, 4>(v, tid, base);
    if constexpr (KK / 2 >= 8)   sstage<KK, 2>(v, tid, base);
    if constexpr (KK / 2 >= 4)   sstage<KK, 1>(v, tid, base);
    rstage<KK>(v, base);
}

// LDS stages (j = jhi .. 256) for kk = 512, 1024 (cross-wave at 256thr x 4)
__device__ __forceinline__ void lds_stage(ull v[4], ull* key, int tid, int base,
                                          int kk, int jhi) {
#pragma unroll
    for (int o = 0; o < 4; ++o) key[base + o] = v[o];
    __syncthreads();
    for (int j = jhi; j >= 256; j >>= 1) {
        for (int t = tid; t < RUN / 2; t += 256) {
            int i  = ((t & ~(j - 1)) << 1) | (t & (j - 1));
            int ix = i | j;
            ull a = key[i], c = key[ix];
            bool up = ((i & kk) == 0);
            if ((a > c) == up) { key[i] = c; key[ix] = a; }
        }
        __syncthreads();
    }
#pragma unroll
    for (int o = 0; o < 4; ++o) v[o] = key[base + o];
}

// ---------------------------------------------------------------------------
// Kernel 1: sort one 1024-element chunk (proven 256thr x 4elem geometry,
// 1280 waves chip-wide). Same bitonic network as R1/R6; only the cross-lane
// primitive changed (DPP for lm=1,2,8). key = (~m)<<32 | idx (unique):
// ascending u64 == descending value, stable by index (= stable argsort(-x)).
// Blocks with r==0 also pack pathway bits (consumed by next launch — safe).
// ---------------------------------------------------------------------------
__global__ __launch_bounds__(256) void chunk_sort(
    const float* __restrict__ expr, const float* __restrict__ pathway,
    ull* __restrict__ runs, ull* __restrict__ pbits, int P, int G)
{
    __shared__ ull key[RUN];
    const int r = blockIdx.x, b = blockIdx.y, tid = threadIdx.x;
    const int base = tid * 4;
    const float* row = expr + (size_t)b * G;

    ull v[4];
#pragma unroll
    for (int o = 0; o < 4; ++o) {
        int i = r * RUN + base + o;
        if (i < G) {
            unsigned u = __float_as_uint(row[i]);
            unsigned m = (u >> 31) ? ~u : (u | 0x80000000u);  // monotone map
            v[o] = ((ull)(~m) << 32) | (unsigned)i;
        } else {
            v[o] = PADKEY;
        }
    }

    sphase<2>(v, tid, base);
    sphase<4>(v, tid, base);
    sphase<8>(v, tid, base);
    sphase<16>(v, tid, base);
    sphase<32>(v, tid, base);
    sphase<64>(v, tid, base);
    sphase<128>(v, tid, base);
    sphase<256>(v, tid, base);
    lds_stage(v, key, tid, base, 512, 256);
    sphase<512>(v, tid, base);
    lds_stage(v, key, tid, base, 1024, 512);
    sphase<1024>(v, tid, base);

    ull* dst = runs + ((size_t)b * NRUN + r) * RUN;
#pragma unroll
    for (int o = 0; o < 4; ++o) dst[base + o] = v[o];

    // Folded pathway pack: blocks with r==0 (64 blocks x 256 thr = 16384 >= G)
    if (r == 0) {
        int g = b * 256 + tid;
        if (g < G) {
            ull m = 0;
#pragma unroll
            for (int p = 0; p < Pc; ++p)
                if (pathway[(size_t)p * G + g] > 0.0f) m |= (1ull << p);
            pbits[g] = m;
        }
    }
}

// ---------------------------------------------------------------------------
// Kernel 2: rank + scatter (R6-proven). Grid (5,64) x 1024: block (rg,b)
// stages all 5 runs (40 KB LDS, 16B loads) and ranks elements
// [rg*1024, rg*1024+1024), one per thread: rank = own-run pos + 4 binary
// searches. Keys unique -> exact bijection onto [0,G). Single fused 16B
// scatter: wp[rank] = { pbits[idx], |v|^0.25 bits }.
// ---------------------------------------------------------------------------
__global__ __launch_bounds__(1024) void rank_scatter(
    const ull* __restrict__ runs, const ull* __restrict__ pbits,
    ulonglong2* __restrict__ wp, int G)
{
    __shared__ ull runsLDS[NPAD];   // 40960 B
    const int rg = blockIdx.x, b = blockIdx.y, tid = threadIdx.x;

    const ulonglong2* r2 = (const ulonglong2*)(runs + (size_t)b * NPAD);
    ulonglong2* l2 = (ulonglong2*)runsLDS;
    for (int i = tid; i < NPAD / 2; i += 1024) l2[i] = r2[i];
    __syncthreads();

    const int e = rg * 1024 + tid;          // 0..5119
    const ull keyv = runsLDS[e];
    if (keyv == PADKEY) return;             // padding

    const int idx = (int)(unsigned)(keyv & 0xFFFFFFFFu);
    const ull pb = pbits[idx];              // issued early, hides under searches

    const int run = e >> 10;
    int rank = e & 1023;                    // own-run position (stable)
#pragma unroll
    for (int rr = 0; rr < NRUN; ++rr) {
        if (rr == run) continue;
        const ull* arr = &runsLDS[rr * RUN];
        int pos = 0;
#pragma unroll
        for (int s = RUN; s >= 1; s >>= 1) {
            int np = pos + s;
            if (np <= RUN && arr[np - 1] < keyv) pos = np;
        }
        rank += pos;
    }

    unsigned m = ~((unsigned)(keyv >> 32));
    unsigned absbits = ((m >> 31) ? m : ~m) & 0x7FFFFFFFu;
    float av = __uint_as_float(absbits);
    ulonglong2 t;
    t.x = pb;
    t.y = (ull)__float_as_uint(sqrtf(sqrtf(av)));   // |v|^0.25
    wp[(size_t)b * G + rank] = t;
}

// ---------------------------------------------------------------------------
// Kernel 3: enrichment scores (R6-verified). Grid (4,64) x 1024 (16 waves):
// wave w = pathway quad qg=w>>2 x gene quarter h=w&3. Norm-factored scan +
// constant-bound (21) unrolled loops; LDS padded to 5376 with zero-step hits.
// ---------------------------------------------------------------------------
__global__ __launch_bounds__(1024) void es_kernel(
    const ulonglong2* __restrict__ wp, float* __restrict__ out,
    int B, int P, int G)
{
    __shared__ float    swq[PADG];   // 21504 B
    __shared__ unsigned sm32[PADG];  // 21504 B
    __shared__ double   cSW[4][4][4];
    __shared__ int      cSH[4][4][4];
    __shared__ double   cBV[4][4][4];
    __shared__ double   cBR[4][4][4];

    const int pg = blockIdx.x;
    const int b  = blockIdx.y;
    const int tid = threadIdx.x;
    const int pbeg = pg * 13;
    const int pend = (pbeg + 13 < P) ? (pbeg + 13) : P;

    for (int i = tid; i < PADG; i += 1024) {
        if (i < G) {
            ulonglong2 t = wp[(size_t)b * G + i];
            swq[i]  = __uint_as_float((unsigned)t.y);
            sm32[i] = (unsigned)(t.x >> pbeg);
        } else {
            swq[i]  = 0.0f;
            sm32[i] = 0xFFFFFFFFu;          // pad = all-hit with wv=0
        }
    }
    __syncthreads();

    const int lane = tid & 63;
    const int w  = tid >> 6;        // 0..15
    const int qg = w >> 2;          // pathway quad 0..3
    const int h  = w & 3;           // gene quarter 0..3
    const int sh4 = qg * 4;

    const int lg = h * 64 + lane;   // chunk id 0..255
    const int start = lg * LPW4;
    int npads = start + LPW4 - G;
    npads = (npads < 0) ? 0 : ((npads > LPW4) ? LPW4 : npads);

    // Pass A: per-chunk (sum w*hit, #hit incl. pads), constant-bound unrolled
    double sw[4] = {0.0, 0.0, 0.0, 0.0};
    int shl[4] = {0, 0, 0, 0};
#pragma unroll
    for (int k = 0; k < LPW4; ++k) {
        int s = start + k;
        unsigned b4 = sm32[s] >> sh4;
        double wv = (double)swq[s];
#pragma unroll
        for (int q = 0; q < 4; ++q) {
            if ((b4 >> q) & 1u) { sw[q] += wv; shl[q]++; }
        }
    }
    // wave totals (real hit counts = shl - npads) -> LDS
#pragma unroll
    for (int q = 0; q < 4; ++q) {
        double s_ = sw[q]; int c_ = shl[q] - npads;
#pragma unroll
        for (int off = 1; off < 64; off <<= 1) {
            s_ += __shfl_xor(s_, off, 64);
            c_ += __shfl_xor(c_, off, 64);
        }
        if (lane == 0) { cSW[qg][h][q] = s_; cSH[qg][h][q] = c_; }
    }
    __syncthreads();

    // Quarter gene counts (real): Qc[h'] = clamp(G - h'*1344, 0, 1344)
    int Qc[4];
#pragma unroll
    for (int hh = 0; hh < 4; ++hh) {
        int c = G - hh * QSPAN;
        Qc[hh] = (c < 0) ? 0 : ((c > QSPAN) ? QSPAN : c);
    }

    // Totals, norm-factored constants, per-lane exclusive prefix
    double negE[4], normq[4], runn[4];
    int shtot[4];
#pragma unroll
    for (int q = 0; q < 4; ++q) {
        double st = 0.0; int ct = 0;
#pragma unroll
        for (int hh = 0; hh < 4; ++hh) { st += cSW[qg][hh][q]; ct += cSH[qg][hh][q]; }
        shtot[q] = ct;
        double d = 1.0 / fmax((double)(G - ct), 1.0);     // inv_denom
        double e = (st > 0.0) ? d * st : d;               // e = inv_denom/norm
        negE[q]  = -e;
        normq[q] = (st > 0.0) ? 1.0 / st : 1.0;
        double offq = 0.0;
        for (int hh = 0; hh < h; ++hh)
            offq += cSW[qg][hh][q] - (double)(Qc[hh] - cSH[qg][hh][q]) * e;
        double csum = sw[q] - (double)(LPW4 - shl[q]) * e;
        double x = csum;
#pragma unroll
        for (int off = 1; off < 64; off <<= 1) {
            double vv = __shfl_up(x, off, 64);
            if (lane >= off) x += vv;
        }
        runn[q] = x - csum + offq;          // exclusive prefix + quarter offset
    }

    // Pass C: constant-bound unrolled scan, no muls in the body
    double bestv[4] = {-1.0, -1.0, -1.0, -1.0};
    double bestr[4] = {0.0, 0.0, 0.0, 0.0};
    int besti[4] = {0x7FFFFFFF, 0x7FFFFFFF, 0x7FFFFFFF, 0x7FFFFFFF};
#pragma unroll
    for (int k = 0; k < LPW4; ++k) {
        int s = start + k;
        unsigned b4 = sm32[s] >> sh4;
        double wv = (double)swq[s];
#pragma unroll
        for (int q = 0; q < 4; ++q) {
            runn[q] += ((b4 >> q) & 1u) ? wv : negE[q];
            double a = fabs(runn[q]);
            if (a > bestv[q]) { bestv[q] = a; bestr[q] = runn[q]; besti[q] = s; }
        }
    }
    // wave-level argmax reduce (first occurrence within quarter)
#pragma unroll
    for (int q = 0; q < 4; ++q) {
#pragma unroll
        for (int off = 1; off < 64; off <<= 1) {
            double ov  = __shfl_xor(bestv[q], off, 64);
            double orr = __shfl_xor(bestr[q], off, 64);
            int    oi  = __shfl_xor(besti[q], off, 64);
            if (ov > bestv[q] || (ov == bestv[q] && oi < besti[q])) {
                bestv[q] = ov; bestr[q] = orr; besti[q] = oi;
            }
        }
        if (lane == 0) { cBV[qg][h][q] = bestv[q]; cBR[qg][h][q] = bestr[q]; }
    }
    __syncthreads();

    // cross-quarter combine + rescale + write (quarters ordered by gene
    // index, so strict > keeps the first occurrence on ties)
    if (h == 0 && lane == 0) {
#pragma unroll
        for (int q = 0; q < 4; ++q) {
            double bv = cBV[qg][0][q];
            double br = cBR[qg][0][q];
#pragma unroll
            for (int hh = 1; hh < 4; ++hh) {
                double v_ = cBV[qg][hh][q];
                if (v_ > bv) { bv = v_; br = cBR[qg][hh][q]; }
            }
            int p = pbeg + sh4 + q;
            if (p < pend)
                out[(size_t)b * P + p] =
                    (shtot[q] > 0) ? (float)(br * normq[q]) : 0.0f;
        }
    }
}

extern "C" void kernel_launch(void* const* d_in, const int* in_sizes, int n_in,
                              void* d_out, int out_size, void* d_ws, size_t ws_size,
                              hipStream_t stream) {
    const float* expr    = (const float*)d_in[0];   // [B, G]
    const float* pathway = (const float*)d_in[1];   // [P, G]
    float* out = (float*)d_out;                     // [B, P]

    // workspace layout (bytes):
    //   pbits ull[5120]        @ 0        (40960)
    //   runs  ull[320*1024]    @ 40960    (2621440 -> ends 2662400)
    //   wp    ull2[B*G]        @ 2662400  (5118976 -> ends 7781376)  ~7.8 MB
    char* ws = (char*)d_ws;
    ull*        pbits = (ull*)ws;
    ull*        runs  = (ull*)(ws + 40960);
    ulonglong2* wp    = (ulonglong2*)(ws + 2662400);

    chunk_sort<<<dim3(NRUN, Bc), dim3(256), 0, stream>>>(
        expr, pathway, runs, pbits, Pc, Gc);
    rank_scatter<<<dim3(NRUN, Bc), dim3(1024), 0, stream>>>(runs, pbits, wp, Gc);
    es_kernel<<<dim3(4, Bc), dim3(1024), 0, stream>>>(
        wp, out, Bc, Pc, Gc);
}